// Round 1
// baseline (37.769 us; speedup 1.0000x reference)
//
#include <hip/hip_runtime.h>
#include <math.h>

// Problem constants (fixed by the reference)
#define H_VAL   7500.0f
#define N_DIM   64
#define T_DIM   65536
#define C_DIM   4
#define BLOCKS_PER_N 32
#define THREADS 256
#define T_PER_BLOCK (T_DIM / BLOCKS_PER_N)   // 2048
#define ITERS (T_PER_BLOCK / THREADS)        // 8

__device__ __forceinline__ float dev_nan() { return __uint_as_float(0x7fc00000u); }
__device__ __forceinline__ bool is_nan(float x) { return x != x; }

// ws layout: ws[n*32 + c*8 + k], k in {sum_o, cnt_o, sum_in, cnt_in, sum_u, cnt_u, sum_e, cnt_e}
__global__ __launch_bounds__(THREADS) void mae_stage1(
        const float* __restrict__ outp, const float* __restrict__ tgtp,
        float* __restrict__ ws) {
    const int n = blockIdx.x / BLOCKS_PER_N;
    const int slice = blockIdx.x % BLOCKS_PER_N;
    const int t0 = slice * T_PER_BLOCK;
    const float h = H_VAL;
    const float eh = 0.1f * H_VAL;   // 750.0f (fp32-exact match to jnp 0.1*h)

    float acc[C_DIM][8];
    #pragma unroll
    for (int c = 0; c < C_DIM; ++c)
        #pragma unroll
        for (int k = 0; k < 8; ++k) acc[c][k] = 0.0f;

    // One float4 = 4 channels of one (n,t) -> fully coalesced 16B/lane loads
    const float4* o4 = reinterpret_cast<const float4*>(outp) + (size_t)n * T_DIM;
    const float4* t4 = reinterpret_cast<const float4*>(tgtp) + (size_t)n * T_DIM;

    #pragma unroll
    for (int it = 0; it < ITERS; ++it) {
        const int t = t0 + it * THREADS + (int)threadIdx.x;
        const float4 ov = o4[t];
        const float4 tv = t4[t];
        const float os[4] = {ov.x, ov.y, ov.z, ov.w};
        const float ts[4] = {tv.x, tv.y, tv.z, tv.w};
        #pragma unroll
        for (int c = 0; c < C_DIM; ++c) {
            const float traw = ts[c];
            const float tc = ((traw > h) || (traw < 0.0f)) ? h : traw;
            const float d = fabsf(os[c] - tc);
            const bool b_o  = (tc == h);
            const bool b_u  = (tc == 0.0f);
            const bool b_in = (tc < h) && (tc > 0.0f);
            const bool b_e  = (tc < eh) && (tc > 0.0f);
            acc[c][0] += b_o  ? d : 0.0f;  acc[c][1] += b_o  ? 1.0f : 0.0f;
            acc[c][2] += b_in ? d : 0.0f;  acc[c][3] += b_in ? 1.0f : 0.0f;
            acc[c][4] += b_u  ? d : 0.0f;  acc[c][5] += b_u  ? 1.0f : 0.0f;
            acc[c][6] += b_e  ? d : 0.0f;  acc[c][7] += b_e  ? 1.0f : 0.0f;
        }
    }

    // 64-lane wave reduce of the 32 accumulators
    #pragma unroll
    for (int c = 0; c < C_DIM; ++c) {
        #pragma unroll
        for (int k = 0; k < 8; ++k) {
            float v = acc[c][k];
            #pragma unroll
            for (int off = 32; off > 0; off >>= 1)
                v += __shfl_down(v, off, 64);
            acc[c][k] = v;
        }
    }

    __shared__ float lds[4][32];
    const int wave = threadIdx.x >> 6;
    const int lane = threadIdx.x & 63;
    if (lane == 0) {
        #pragma unroll
        for (int c = 0; c < C_DIM; ++c)
            #pragma unroll
            for (int k = 0; k < 8; ++k)
                lds[wave][c * 8 + k] = acc[c][k];
    }
    __syncthreads();
    if (threadIdx.x < 32) {
        const float v = lds[0][threadIdx.x] + lds[1][threadIdx.x] +
                        lds[2][threadIdx.x] + lds[3][threadIdx.x];
        atomicAdd(&ws[n * 32 + (int)threadIdx.x], v);
    }
}

__global__ __launch_bounds__(256) void mae_stage2(
        const float* __restrict__ ws, float* __restrict__ outp) {
    const int i = threadIdx.x;            // 0..255 == (n,c) pair
    const int n = i >> 2, c = i & 3;
    const float* a = &ws[n * 32 + c * 8];

    const float m_o  = (a[1] > 0.0f) ? a[0] / a[1] : dev_nan();
    const float m_in = (a[3] > 0.0f) ? a[2] / a[3] : dev_nan();
    const float m_u  = (a[5] > 0.0f) ? a[4] / a[5] : dev_nan();
    const float m_e  = (a[7] > 0.0f) ? a[6] / a[7] : dev_nan();

    // nanmean over a pair
    auto nm2 = [](float x, float y) {
        const bool vx = !is_nan(x), vy = !is_nan(y);
        const float s  = (vx ? x : 0.0f) + (vy ? y : 0.0f);
        const float cc = (vx ? 1.0f : 0.0f) + (vy ? 1.0f : 0.0f);
        return (cc > 0.0f) ? s / cc : dev_nan();
    };
    const float in_comb = nm2(m_u, m_in);
    const float w       = nm2(m_o, in_comb);

    float vals[4] = {w, in_comb, m_o, m_e};   // -> wMAE, inMAE, oMAE, eMAE
    float sums[4], cnts[4];
    #pragma unroll
    for (int j = 0; j < 4; ++j) {
        const bool v = !is_nan(vals[j]);
        sums[j] = v ? vals[j] : 0.0f;
        cnts[j] = v ? 1.0f : 0.0f;
    }
    #pragma unroll
    for (int j = 0; j < 4; ++j) {
        #pragma unroll
        for (int off = 32; off > 0; off >>= 1) {
            sums[j] += __shfl_down(sums[j], off, 64);
            cnts[j] += __shfl_down(cnts[j], off, 64);
        }
    }
    __shared__ float ls[4][8];
    const int wave = threadIdx.x >> 6;
    const int lane = threadIdx.x & 63;
    if (lane == 0) {
        #pragma unroll
        for (int j = 0; j < 4; ++j) { ls[wave][j] = sums[j]; ls[wave][j + 4] = cnts[j]; }
    }
    __syncthreads();
    if (threadIdx.x == 0) {
        #pragma unroll
        for (int j = 0; j < 4; ++j) {
            const float s  = ls[0][j] + ls[1][j] + ls[2][j] + ls[3][j];
            const float cc = ls[0][j + 4] + ls[1][j + 4] + ls[2][j + 4] + ls[3][j + 4];
            outp[j] = (cc > 0.0f) ? s / cc : dev_nan();
        }
    }
}

extern "C" void kernel_launch(void* const* d_in, const int* in_sizes, int n_in,
                              void* d_out, int out_size, void* d_ws, size_t ws_size,
                              hipStream_t stream) {
    const float* out_rsd = (const float*)d_in[0];
    const float* tgt_rsd = (const float*)d_in[1];
    float* outv = (float*)d_out;
    float* ws = (float*)d_ws;

    // Zero the 8 KB accumulator workspace every call (harness does not re-poison).
    hipMemsetAsync(ws, 0, N_DIM * 32 * sizeof(float), stream);

    mae_stage1<<<N_DIM * BLOCKS_PER_N, THREADS, 0, stream>>>(out_rsd, tgt_rsd, ws);
    mae_stage2<<<1, 256, 0, stream>>>(ws, outv);
}